// Round 1
// baseline (2373.306 us; speedup 1.0000x reference)
//
#include <hip/hip_runtime.h>
#include <math.h>

#define D_ 64
#define H_ 32
#define TPB 256
#define PAD 65   // LDS row stride in floats: (65*i+k)%32=(i+k)%32 -> 2-way = free

static constexpr float K_SCALE   = 173.71779276130071f;  // 400/ln(10)
static constexpr float K_DEFAULT = 7.6699353278706015f;

__global__ __launch_bounds__(TPB, 2)
void poc_main(const float* __restrict__ x,
              const float* __restrict__ W1,
              const float* __restrict__ b1,
              const float* __restrict__ wr,
              const float* __restrict__ brp,
              const float* __restrict__ wz,
              const float* __restrict__ bzp,
              const int* __restrict__ seg,
              float* __restrict__ denom,
              float* __restrict__ numer,
              int N)
{
    __shared__ float sx[TPB * PAD];   // 66,560 B -> 2 blocks/CU
    const int tid = threadIdx.x;
    const long long rowBase = (long long)blockIdx.x * TPB;

    // ---- stage x tile (256 rows x 64 cols) into LDS, coalesced float4 ----
    if (rowBase + TPB <= (long long)N) {
        const float4* xg = (const float4*)(x + rowBase * D_);
        #pragma unroll
        for (int it = 0; it < 16; ++it) {
            int v = it * TPB + tid;            // float4 index within tile
            float4 val = xg[v];
            float* dst = &sx[(v >> 4) * PAD + (v & 15) * 4];
            dst[0] = val.x; dst[1] = val.y; dst[2] = val.z; dst[3] = val.w;
        }
    } else {  // tail tile (not hit for N=4M but kept for generality)
        #pragma unroll
        for (int it = 0; it < 16; ++it) {
            int v = it * TPB + tid;
            long long row = rowBase + (v >> 4);
            float4 val = make_float4(0.f, 0.f, 0.f, 0.f);
            if (row < (long long)N) val = ((const float4*)x)[row * 16 + (v & 15)];
            float* dst = &sx[(v >> 4) * PAD + (v & 15) * 4];
            dst[0] = val.x; dst[1] = val.y; dst[2] = val.z; dst[3] = val.w;
        }
    }
    __syncthreads();

    // ---- row into registers ----
    float xr[D_];
    #pragma unroll
    for (int k = 0; k < D_; ++k) xr[k] = sx[tid * PAD + k];

    // ---- tiny MLP: h = relu(x@W1 + b1); r = h@wr+br; z = h@wz+bz ----
    // W1/b1/wr/wz indices are wave-uniform -> scalar loads (no VALU cost).
    float rr = *brp;
    float zz = *bzp;
    #pragma unroll 4
    for (int j = 0; j < H_; ++j) {
        float a0 = b1[j], a1 = 0.0f;   // 2 chains for FMA-latency ILP
        #pragma unroll
        for (int k = 0; k < D_; k += 2) {
            a0 = fmaf(xr[k],     W1[k * H_ + j],       a0);
            a1 = fmaf(xr[k + 1], W1[(k + 1) * H_ + j], a1);
        }
        float h = fmaxf(a0 + a1, 0.0f);
        rr = fmaf(h, wr[j], rr);
        zz = fmaf(h, wz[j], zz);
    }

    // ---- softmax weights: exp(z) directly (|z| small; numer/denom is
    //      invariant to the reference's max-subtraction) ----
    long long row = rowBase + tid;
    int sid;
    float ez, ezr;
    if (row < (long long)N) {
        sid = seg[row];
        ez  = __expf(zz);
        ezr = ez * rr;
    } else {
        sid = seg[N - 1];   // zero contribution is safe anywhere
        ez = 0.0f; ezr = 0.0f;
    }

    // ---- per-wave segmented inclusive scan (ids sorted -> few segs/wave) ----
    const int lane = tid & 63;
    #pragma unroll
    for (int off = 1; off < 64; off <<= 1) {
        float au = __shfl_up(ez,  off, 64);
        float bu = __shfl_up(ezr, off, 64);
        int   su = __shfl_up(sid, off, 64);
        if (lane >= off && su == sid) { ez += au; ezr += bu; }
    }
    int sdn = __shfl_down(sid, 1, 64);
    if (lane == 63 || sdn != sid) {       // last lane of each segment run
        atomicAdd(&denom[sid], ez);
        atomicAdd(&numer[sid], ezr);
    }
}

__global__ void poc_final(const float* __restrict__ denom,
                          const float* __restrict__ numer,
                          float* __restrict__ out, int S)
{
    int i = blockIdx.x * blockDim.x + threadIdx.x;
    if (i < S) {
        float d = denom[i];
        // exp(z) > 0 for any contribution, so d == 0 <=> empty segment
        out[i] = (d > 0.0f) ? (K_SCALE * numer[i] / d) : (K_SCALE * K_DEFAULT);
    }
}

extern "C" void kernel_launch(void* const* d_in, const int* in_sizes, int n_in,
                              void* d_out, int out_size, void* d_ws, size_t ws_size,
                              hipStream_t stream)
{
    const float* x   = (const float*)d_in[0];
    const float* W1  = (const float*)d_in[1];
    const float* b1  = (const float*)d_in[2];
    const float* wr  = (const float*)d_in[3];
    const float* br  = (const float*)d_in[4];
    const float* wz  = (const float*)d_in[5];
    const float* bz  = (const float*)d_in[6];
    const int*   seg = (const int*)d_in[7];

    const int N = in_sizes[7];     // 4,194,304 rows
    const int S = out_size;        // 16,384 segments

    float* denom = (float*)d_ws;
    float* numer = denom + S;
    hipMemsetAsync(d_ws, 0, (size_t)2 * S * sizeof(float), stream);

    int nblocks = (N + TPB - 1) / TPB;
    poc_main<<<nblocks, TPB, 0, stream>>>(x, W1, b1, wr, br, wz, bz, seg,
                                          denom, numer, N);
    poc_final<<<(S + 255) / 256, 256, 0, stream>>>(denom, numer, (float*)d_out, S);
}